// Round 12
// baseline (182.954 us; speedup 1.0000x reference)
//
#include <hip/hip_runtime.h>
#include <hip/hip_fp16.h>

#define N_NODES 100000
#define N_EDGES 1600000
#define K_DIM   128

#define CHUNK_LG 7
#define CHUNK    128                                     // nodes per bucket
#define NBKT     ((N_NODES + CHUNK - 1) / CHUNK)         // 782
#define CAP      2560                                    // mean 2046 + ~11 sigma
#define EPB      4096                                    // edges per bucket-block
#define NBLK_A   ((N_EDGES + EPB - 1) / EPB)             // 391
#define G1_BLOCKS ((N_NODES + 63) / 64)                  // 1563 gemm tiles

#define K1_TILES 782                                     // gemm tiles in K1
#define K1_TOTAL (3 * NBLK_A)                            // 1173 = 391*[b,g,g]
#define K2_TILES (G1_BLOCKS - K1_TILES)                  // 781
#define K2_TOTAL (NBKT + K2_TILES)                       // 1563 = [f,g] pairs

typedef _Float16 half8 __attribute__((ext_vector_type(8)));
typedef float    f32x4 __attribute__((ext_vector_type(4)));

// ============ one-shot: W -> f16 transposed Wt[n][k]; also zero gcur ======
__global__ __launch_bounds__(256) void k_prepW(const float* __restrict__ W1,
                                               const float* __restrict__ W2,
                                               _Float16* __restrict__ Wt1,
                                               _Float16* __restrict__ Wt2,
                                               int* __restrict__ gcur) {
    if (blockIdx.x >= 12) {                   // blocks 12..15: zero cursors
        int i = (blockIdx.x - 12) * 256 + threadIdx.x;
        if (i < NBKT) gcur[i] = 0;
        return;
    }
    int c = blockIdx.x * 256 + threadIdx.x;   // 3072 chunks of 8
    const float* W; _Float16* Wt; int nout;
    if (c < 2048) { W = W1; Wt = Wt1; nout = 128; }
    else          { W = W2; Wt = Wt2; nout = 64; c -= 2048; }
    int n  = c >> 4;
    int k0 = (c & 15) * 8;
    half8 v;
#pragma unroll
    for (int j = 0; j < 8; ++j)
        v[j] = (_Float16)W[(size_t)(k0 + j) * nout + n];
    *reinterpret_cast<half8*>(Wt + (size_t)n * K_DIM + k0) = v;
}

// ============ device paths shared by the two fused kernels ================

// gemm1 tile: h1[tile*64 .. +64) = x @ W1  (f16 out)
__device__ __forceinline__ void gemm1_tile(char* smem, int tile,
    const float* __restrict__ x, const _Float16* __restrict__ Wt,
    _Float16* __restrict__ Hout)
{
    constexpr int KD = K_DIM, NOUT = 128, NT = NOUT / 16;
    _Float16 (*Blds)[KD + 8] = reinterpret_cast<_Float16(*)[KD + 8]>(smem);

    for (int i = threadIdx.x; i < NOUT * (KD / 8); i += 256) {
        int n = i >> 4, k0 = (i & 15) * 8;
        *reinterpret_cast<half8*>(&Blds[n][k0]) =
            *reinterpret_cast<const half8*>(Wt + (size_t)n * KD + k0);
    }
    __syncthreads();

    const int wave = threadIdx.x >> 6;
    const int lane = threadIdx.x & 63;
    const int r16  = lane & 15;
    const int kg   = lane >> 4;
    const int arow = tile * 64 + wave * 16 + r16;
    const bool rowok = arow < N_NODES;

    f32x4 acc[NT];
#pragma unroll
    for (int ct = 0; ct < NT; ++ct) acc[ct] = (f32x4){0.f, 0.f, 0.f, 0.f};

#pragma unroll
    for (int kc = 0; kc < KD / 32; ++kc) {
        const int k0 = kc * 32 + kg * 8;
        float4 xa = make_float4(0.f, 0.f, 0.f, 0.f), xb = xa;
        if (rowok) {
            const float4* ap = reinterpret_cast<const float4*>(
                x + (size_t)arow * KD + k0);
            xa = ap[0]; xb = ap[1];
        }
        half8 a;
        a[0] = (_Float16)xa.x; a[1] = (_Float16)xa.y;
        a[2] = (_Float16)xa.z; a[3] = (_Float16)xa.w;
        a[4] = (_Float16)xb.x; a[5] = (_Float16)xb.y;
        a[6] = (_Float16)xb.z; a[7] = (_Float16)xb.w;
#pragma unroll
        for (int ct = 0; ct < NT; ++ct) {
            half8 b = *reinterpret_cast<const half8*>(&Blds[ct * 16 + r16][k0]);
            acc[ct] = __builtin_amdgcn_mfma_f32_16x16x32_f16(a, b, acc[ct], 0, 0, 0);
        }
    }

    const int orow0 = tile * 64 + wave * 16 + kg * 4;
#pragma unroll
    for (int r = 0; r < 4; ++r) {
        int orow = orow0 + r;
        if (orow < N_NODES) {
#pragma unroll
            for (int ct = 0; ct < NT; ++ct)
                Hout[(size_t)orow * NOUT + ct * 16 + r16] = (_Float16)acc[ct][r];
        }
    }
}

// bucket block bb: partition EPB edges into per-bucket pair regions
__device__ __forceinline__ void bucket_path(char* smem, int bb,
    const int* __restrict__ row, const int* __restrict__ col,
    int* __restrict__ gcur, int* __restrict__ pairs)
{
    int* hist  = (int*)smem;           // [1024]
    int* sbase = hist + 1024;          // [1024]
    int* lcur  = hist + 2048;          // [1024]
    int t = threadIdx.x;
    for (int i = t; i < NBKT; i += 256) { hist[i] = 0; lcur[i] = 0; }
    __syncthreads();
    int base = bb * EPB;
    int myb[16], myp[16];
#pragma unroll
    for (int j = 0; j < 16; ++j) {
        int i = base + t + j * 256;
        int b = -1, p = 0;
        if (i < N_EDGES) {
            int r = row[i], c = col[i];
            b = c >> CHUNK_LG;
            p = ((c & (CHUNK - 1)) << 17) | r;       // row < 2^17
            atomicAdd(&hist[b], 1);
        }
        myb[j] = b; myp[j] = p;
    }
    __syncthreads();
    for (int i = t; i < NBKT; i += 256) {
        int c = hist[i];
        sbase[i] = c ? atomicAdd(&gcur[i], c) : 0;
    }
    __syncthreads();
#pragma unroll
    for (int j = 0; j < 16; ++j) {
        int b = myb[j];
        if (b >= 0) {
            int pos = sbase[b] + atomicAdd(&lcur[b], 1);
            pairs[(size_t)b * CAP + pos] = myp[j];
        }
    }
}

// fill block b: bucket -> rowptr, dinv, srows
__device__ __forceinline__ void fill_path(char* smem, int b,
    const int* __restrict__ gcur, const int* __restrict__ pairs,
    int* __restrict__ rowptr, float* __restrict__ dinv,
    int* __restrict__ srows)
{
    int* mpl  = (int*)smem;            // [CAP]
    int* red  = mpl + CAP;             // [256]
    int* psum = red + 256;             // [CHUNK]
    int* deg  = psum + CHUNK;          // [CHUNK]
    int* curs = deg + CHUNK;           // [CHUNK]
    int t = threadIdx.x;

    // global base = sum gcur[0..b-1]
    int part = 0;
    for (int i = t; i < NBKT; i += 256)
        if (i < b) part += gcur[i];
    red[t] = part;
    if (t < CHUNK) deg[t] = 0;
    __syncthreads();
    for (int off = 128; off; off >>= 1) {
        if (t < off) red[t] += red[t + off];
        __syncthreads();
    }
    int gb = red[0];
    int cnt = gcur[b];
    if (b == 0 && t == 0) rowptr[N_NODES] = N_EDGES;

    const int* mp = pairs + (size_t)b * CAP;

    for (int i = t; i < cnt; i += 256) {
        int v = mp[i];
        mpl[i] = v;
        atomicAdd(&deg[v >> 17], 1);
    }
    __syncthreads();

    int d = (t < CHUNK) ? deg[t] : 0;
    if (t < CHUNK) psum[t] = d;
    __syncthreads();
    for (int off = 1; off < CHUNK; off <<= 1) {
        int u = (t >= off && t < CHUNK) ? psum[t - off] : 0;
        __syncthreads();
        if (t < CHUNK) psum[t] += u;
        __syncthreads();
    }
    if (t < CHUNK) {
        int o = gb + psum[t] - d;                 // exclusive
        curs[t] = o;
        int node = (b << CHUNK_LG) + t;
        if (node < N_NODES) {
            rowptr[node] = o;
            dinv[node] = rsqrtf(1.f + (float)d);
        }
    }
    __syncthreads();
    for (int i = t; i < cnt; i += 256) {
        int v = mpl[i];
        int pos = atomicAdd(&curs[v >> 17], 1);
        srows[pos] = v & 0x1FFFF;
    }
}

// ============ K1: bucket(391) ∥ gemm1 tiles 0..781 ========================
// groups of 3: [bucket, gemm, gemm]
__global__ __launch_bounds__(256) void k_stage1(
    const float* __restrict__ x, const _Float16* __restrict__ Wt,
    _Float16* __restrict__ Hout,
    const int* __restrict__ row, const int* __restrict__ col,
    int* __restrict__ gcur, int* __restrict__ pairs)
{
    __shared__ __align__(16) char smem[128 * 136 * 2];   // 34816 B
    int bid = blockIdx.x;
    if (bid % 3 == 0)
        bucket_path(smem, bid / 3, row, col, gcur, pairs);
    else
        gemm1_tile(smem, (bid / 3) * 2 + (bid % 3) - 1, x, Wt, Hout);
}

// ============ K2: fillB(782) ∥ gemm1 tiles 782..1562 ======================
// alternating [fill, gemm]
__global__ __launch_bounds__(256) void k_stage2(
    const float* __restrict__ x, const _Float16* __restrict__ Wt,
    _Float16* __restrict__ Hout,
    const int* __restrict__ gcur, const int* __restrict__ pairs,
    int* __restrict__ rowptr, float* __restrict__ dinv,
    int* __restrict__ srows)
{
    __shared__ __align__(16) char smem[128 * 136 * 2];   // 34816 B
    int bid = blockIdx.x;
    if ((bid & 1) == 0)
        fill_path(smem, bid >> 1, gcur, pairs, rowptr, dinv, srows);
    else
        gemm1_tile(smem, K1_TILES + (bid >> 1), x, Wt, Hout);
}

// ============ layer-2 GEMM: h2 = relu(agg1+b1)@W2, f16 out ================
template<int NOUT>
__global__ __launch_bounds__(256) void k_gemm_mfma2(
    const _Float16* __restrict__ Ah, const _Float16* __restrict__ Wt,
    const float* __restrict__ b_in, _Float16* __restrict__ Hout, int nrows)
{
    constexpr int KD = K_DIM;
    constexpr int NT = NOUT / 16;
    __shared__ _Float16 Blds[NOUT][KD + 8];

    for (int i = threadIdx.x; i < NOUT * (KD / 8); i += 256) {
        int n = i >> 4, k0 = (i & 15) * 8;
        *reinterpret_cast<half8*>(&Blds[n][k0]) =
            *reinterpret_cast<const half8*>(Wt + (size_t)n * KD + k0);
    }
    __syncthreads();

    const int wave = threadIdx.x >> 6;
    const int lane = threadIdx.x & 63;
    const int r16  = lane & 15;
    const int kg   = lane >> 4;
    const int arow = blockIdx.x * 64 + wave * 16 + r16;
    const bool rowok = arow < nrows;

    f32x4 acc[NT];
#pragma unroll
    for (int ct = 0; ct < NT; ++ct) acc[ct] = (f32x4){0.f, 0.f, 0.f, 0.f};

#pragma unroll
    for (int kc = 0; kc < KD / 32; ++kc) {
        const int k0 = kc * 32 + kg * 8;
        uint4 raw = make_uint4(0, 0, 0, 0);
        if (rowok)
            raw = *reinterpret_cast<const uint4*>(Ah + (size_t)arow * KD + k0);
        union { uint4 u; _Float16 h[8]; } U; U.u = raw;
        float4 bA = *reinterpret_cast<const float4*>(b_in + k0);
        float4 bB = *reinterpret_cast<const float4*>(b_in + k0 + 4);
        half8 a;
        a[0] = (_Float16)fmaxf((float)U.h[0] + bA.x, 0.f);
        a[1] = (_Float16)fmaxf((float)U.h[1] + bA.y, 0.f);
        a[2] = (_Float16)fmaxf((float)U.h[2] + bA.z, 0.f);
        a[3] = (_Float16)fmaxf((float)U.h[3] + bA.w, 0.f);
        a[4] = (_Float16)fmaxf((float)U.h[4] + bB.x, 0.f);
        a[5] = (_Float16)fmaxf((float)U.h[5] + bB.y, 0.f);
        a[6] = (_Float16)fmaxf((float)U.h[6] + bB.z, 0.f);
        a[7] = (_Float16)fmaxf((float)U.h[7] + bB.w, 0.f);
#pragma unroll
        for (int ct = 0; ct < NT; ++ct) {
            half8 b = *reinterpret_cast<const half8*>(&Blds[ct * 16 + r16][k0]);
            acc[ct] = __builtin_amdgcn_mfma_f32_16x16x32_f16(a, b, acc[ct], 0, 0, 0);
        }
    }

    const int orow0 = blockIdx.x * 64 + wave * 16 + kg * 4;
#pragma unroll
    for (int r = 0; r < 4; ++r) {
        int orow = orow0 + r;
        if (orow < nrows) {
#pragma unroll
            for (int ct = 0; ct < NT; ++ct)
                Hout[(size_t)orow * NOUT + ct * 16 + r16] = (_Float16)acc[ct][r];
        }
    }
}

// ---------------- gather (f16 source): TWO nodes per wave ----------------
__device__ __forceinline__ void fma8(uint4 v, float wgt, float (&acc)[8]) {
    union { uint4 u; _Float16 h[8]; } U;
    U.u = v;
#pragma unroll
    for (int j = 0; j < 8; ++j)
        acc[j] = fmaf((float)U.h[j], wgt, acc[j]);
}

// OUT[i] = sum_e H[row_e]*dinv_r*dinv_i + H[i]*dinv_i^2 (+bias)
template<int F, bool OUT_HALF>
__global__ __launch_bounds__(256) void k_gather_h(
    const int* __restrict__ rowptr, const int* __restrict__ srows,
    const float* __restrict__ dinv, const _Float16* __restrict__ H,
    const float* __restrict__ bias, void* __restrict__ OUT, int n)
{
    constexpr int LPR = F / 8;     // lanes per row (16 or 8)
    constexpr int GR  = 32 / LPR;  // rows per half-wave load (2 or 4)
    int lane = threadIdx.x & 63;
    int half = lane >> 5;
    int hl   = lane & 31;
    int w = blockIdx.x * 8 + (threadIdx.x >> 6) * 2 + half;
    if (w >= n) return;
    int g = hl / LPR;              // row group within half-wave
    int c = hl % LPR;              // uint4 slot within row
    float di = dinv[w];
    int s = rowptr[w], e = rowptr[w + 1];
    const uint4* Hp = reinterpret_cast<const uint4*>(H);

    float acc[8];
#pragma unroll
    for (int j = 0; j < 8; ++j) acc[j] = 0.f;
    uint4 hv = Hp[(size_t)w * LPR + c];                 // self row
    fma8(hv, (g == 0) ? di * di : 0.f, acc);

    if (s < e) {
        int k0 = s + g;
        int kc = min(k0, e - 1);
        int r  = srows[kc];
        float wcur = (k0 < e) ? dinv[r] * di : 0.f;
        uint4 hcur = Hp[(size_t)r * LPR + c];
        for (int k = s + GR; k < e; k += GR) {
            int k1  = k + g;
            int kc1 = min(k1, e - 1);
            int r1  = srows[kc1];
            float wnxt = (k1 < e) ? dinv[r1] * di : 0.f;
            uint4 hnxt = Hp[(size_t)r1 * LPR + c];
            fma8(hcur, wcur, acc);
            wcur = wnxt; hcur = hnxt;
        }
        fma8(hcur, wcur, acc);
    }

#pragma unroll
    for (int m = 16; m >= LPR; m >>= 1) {               // combine row groups
#pragma unroll
        for (int j = 0; j < 8; ++j)
            acc[j] += __shfl_xor(acc[j], m, 64);
    }

    if (g == 0) {
        if constexpr (OUT_HALF) {
            union { uint4 u; __half2 h[4]; } P;
#pragma unroll
            for (int j = 0; j < 4; ++j)
                P.h[j] = __floats2half2_rn(acc[2 * j], acc[2 * j + 1]);
            reinterpret_cast<uint4*>(OUT)[(size_t)w * LPR + c] = P.u;
        } else {
            const float4* bp = reinterpret_cast<const float4*>(bias + c * 8);
            float4 b0 = bp[0], b1v = bp[1];
            float4 o0 = make_float4(acc[0] + b0.x, acc[1] + b0.y,
                                    acc[2] + b0.z, acc[3] + b0.w);
            float4 o1 = make_float4(acc[4] + b1v.x, acc[5] + b1v.y,
                                    acc[6] + b1v.z, acc[7] + b1v.w);
            float* op = (float*)OUT + (size_t)w * F + c * 8;
            *reinterpret_cast<float4*>(op)     = o0;
            *reinterpret_cast<float4*>(op + 4) = o1;
        }
    }
}

// ---------------- launch ----------------

extern "C" void kernel_launch(void* const* d_in, const int* in_sizes, int n_in,
                              void* d_out, int out_size, void* d_ws, size_t ws_size,
                              hipStream_t stream) {
    const float* x  = (const float*)d_in[0];
    const int*   ei = (const int*)  d_in[1];
    const float* W1 = (const float*)d_in[2];
    const float* b1 = (const float*)d_in[3];
    const float* W2 = (const float*)d_in[4];
    const float* b2 = (const float*)d_in[5];
    float* out = (float*)d_out;

    const int* row = ei;             // sources
    const int* col = ei + N_EDGES;   // targets

    // workspace layout
    char* ws = (char*)d_ws;
    int*   gcur   = (int*)ws;                                      // NBKT (782)
    int*   rowptr = gcur + 1024;                                   // N+1
    float* dinv   = (float*)(rowptr + ((N_NODES + 256) & ~255));   // N
    int*   srows  = (int*)(dinv + ((N_NODES + 255) & ~255));       // E
    _Float16* bufH  = (_Float16*)(srows + ((N_EDGES + 255) & ~255)); // N*128 (h1)
    _Float16* bufAgg = bufH + (size_t)N_NODES * 128;               // N*128 (agg1)
    _Float16* bufH2  = bufAgg + (size_t)N_NODES * 128;             // N*64 (h2)
    _Float16* Wt1 = bufH2 + (size_t)N_NODES * 64;                  // 128*128
    _Float16* Wt2 = Wt1 + 128 * 128;                               // 64*128
    int*   pairs  = (int*)(Wt2 + 64 * 128 + 256);                  // NBKT*CAP (8MB)

    // 0) W -> f16 transposed + zero bucket cursors
    k_prepW<<<16, 256, 0, stream>>>(W1, W2, Wt1, Wt2, gcur);

    // 1) K1: bucket ∥ gemm1 (tiles 0..781)
    k_stage1<<<K1_TOTAL, 256, 0, stream>>>(
        x, Wt1, bufH, row, col, gcur, pairs);

    // 2) K2: fillB ∥ gemm1 (tiles 782..1562)
    k_stage2<<<K2_TOTAL, 256, 0, stream>>>(
        x, Wt1, bufH, gcur, pairs, rowptr, dinv, srows);

    // 3) agg1 = gather(h1), f16 out  (2 nodes per wave)
    k_gather_h<128, true><<<(N_NODES + 7) / 8, 256, 0, stream>>>(
        rowptr, srows, dinv, bufH, nullptr, bufAgg, N_NODES);

    // 4) h2 = relu(agg1+b1)@W2 (f16 out)
    k_gemm_mfma2<64><<<(N_NODES + 63) / 64, 256, 0, stream>>>(
        bufAgg, Wt2, b1, bufH2, N_NODES);

    // 5) out = gather(h2) + b2 (fp32 out, 2 nodes per wave)
    k_gather_h<64, false><<<(N_NODES + 7) / 8, 256, 0, stream>>>(
        rowptr, srows, dinv, bufH2, b2, out, N_NODES);
}

// Round 13
// 176.969 us; speedup vs baseline: 1.0338x; 1.0338x over previous
//
#include <hip/hip_runtime.h>
#include <hip/hip_fp16.h>

#define N_NODES 100000
#define N_EDGES 1600000
#define K_DIM   128

#define CHUNK_LG 7
#define CHUNK    128                                     // nodes per bucket
#define NBKT     ((N_NODES + CHUNK - 1) / CHUNK)         // 782
#define CAP      2560                                    // mean 2046 + ~11 sigma
#define EPB      4096                                    // edges per bucket-block
#define NBLK_A   ((N_EDGES + EPB - 1) / EPB)             // 391
#define G1_BLOCKS ((N_NODES + 63) / 64)                  // 1563 gemm tiles
#define NBLK_TOT (G1_BLOCKS + NBLK_A)                    // 1954

typedef _Float16 half8 __attribute__((ext_vector_type(8)));
typedef float    f32x4 __attribute__((ext_vector_type(4)));

// ============ one-shot: W -> f16 transposed Wt[n][k]; also zero gcur ======
__global__ __launch_bounds__(256) void k_prepW(const float* __restrict__ W1,
                                               const float* __restrict__ W2,
                                               _Float16* __restrict__ Wt1,
                                               _Float16* __restrict__ Wt2,
                                               int* __restrict__ gcur) {
    if (blockIdx.x >= 12) {                   // blocks 12..15: zero cursors
        int i = (blockIdx.x - 12) * 256 + threadIdx.x;
        if (i < NBKT) gcur[i] = 0;
        return;
    }
    int c = blockIdx.x * 256 + threadIdx.x;   // 3072 chunks of 8
    const float* W; _Float16* Wt; int nout;
    if (c < 2048) { W = W1; Wt = Wt1; nout = 128; }
    else          { W = W2; Wt = Wt2; nout = 64; c -= 2048; }
    int n  = c >> 4;
    int k0 = (c & 15) * 8;
    half8 v;
#pragma unroll
    for (int j = 0; j < 8; ++j)
        v[j] = (_Float16)W[(size_t)(k0 + j) * nout + n];
    *reinterpret_cast<half8*>(Wt + (size_t)n * K_DIM + k0) = v;
}

// ============ fused: gemm1 (h1 = x@W1, f16 out)  ∥  edge bucketing ========
// bid%5==0 -> bucket block (391, EPB=4096); else GEMM tile (1563).
__global__ __launch_bounds__(256) void k_gemm1_bucket(
    const float* __restrict__ x, const _Float16* __restrict__ Wt,
    _Float16* __restrict__ Hout,
    const int* __restrict__ row, const int* __restrict__ col,
    int* __restrict__ gcur, int* __restrict__ pairs)
{
    __shared__ __align__(16) char smem[128 * 136 * 2];   // 34816 B

    if (blockIdx.x % 5 != 0) {
        // ---------------- gemm path: NOUT=128, A fp32 ----------------
        constexpr int KD = K_DIM, NOUT = 128, NT = NOUT / 16;
        _Float16 (*Blds)[KD + 8] = reinterpret_cast<_Float16(*)[KD + 8]>(smem);

        for (int i = threadIdx.x; i < NOUT * (KD / 8); i += 256) {
            int n = i >> 4, k0 = (i & 15) * 8;
            *reinterpret_cast<half8*>(&Blds[n][k0]) =
                *reinterpret_cast<const half8*>(Wt + (size_t)n * KD + k0);
        }
        __syncthreads();

        const int tile = blockIdx.x - blockIdx.x / 5 - 1;
        const int wave = threadIdx.x >> 6;
        const int lane = threadIdx.x & 63;
        const int r16  = lane & 15;
        const int kg   = lane >> 4;
        const int arow = tile * 64 + wave * 16 + r16;
        const bool rowok = arow < N_NODES;

        f32x4 acc[NT];
#pragma unroll
        for (int ct = 0; ct < NT; ++ct) acc[ct] = (f32x4){0.f, 0.f, 0.f, 0.f};

#pragma unroll
        for (int kc = 0; kc < KD / 32; ++kc) {
            const int k0 = kc * 32 + kg * 8;
            float4 xa = make_float4(0.f, 0.f, 0.f, 0.f), xb = xa;
            if (rowok) {
                const float4* ap = reinterpret_cast<const float4*>(
                    x + (size_t)arow * KD + k0);
                xa = ap[0]; xb = ap[1];
            }
            half8 a;
            a[0] = (_Float16)xa.x; a[1] = (_Float16)xa.y;
            a[2] = (_Float16)xa.z; a[3] = (_Float16)xa.w;
            a[4] = (_Float16)xb.x; a[5] = (_Float16)xb.y;
            a[6] = (_Float16)xb.z; a[7] = (_Float16)xb.w;
#pragma unroll
            for (int ct = 0; ct < NT; ++ct) {
                half8 b = *reinterpret_cast<const half8*>(&Blds[ct * 16 + r16][k0]);
                acc[ct] = __builtin_amdgcn_mfma_f32_16x16x32_f16(a, b, acc[ct], 0, 0, 0);
            }
        }

        const int orow0 = tile * 64 + wave * 16 + kg * 4;
#pragma unroll
        for (int r = 0; r < 4; ++r) {
            int orow = orow0 + r;
            if (orow < N_NODES) {
#pragma unroll
                for (int ct = 0; ct < NT; ++ct)
                    Hout[(size_t)orow * NOUT + ct * 16 + r16] = (_Float16)acc[ct][r];
            }
        }
    } else {
        // ---------------- bucket path: EPB=4096, 16 edges/thread ---------
        int* hist  = (int*)smem;           // [1024]
        int* sbase = hist + 1024;          // [1024]
        int* lcur  = hist + 2048;          // [1024]
        int t = threadIdx.x;
        for (int i = t; i < NBKT; i += 256) { hist[i] = 0; lcur[i] = 0; }
        __syncthreads();
        int base = (blockIdx.x / 5) * EPB;
        int myb[16], myp[16];
#pragma unroll
        for (int j = 0; j < 16; ++j) {
            int i = base + t + j * 256;
            int b = -1, p = 0;
            if (i < N_EDGES) {
                int r = row[i], c = col[i];
                b = c >> CHUNK_LG;
                p = ((c & (CHUNK - 1)) << 17) | r;       // row < 2^17
                atomicAdd(&hist[b], 1);
            }
            myb[j] = b; myp[j] = p;
        }
        __syncthreads();
        for (int i = t; i < NBKT; i += 256) {
            int c = hist[i];
            sbase[i] = c ? atomicAdd(&gcur[i], c) : 0;
        }
        __syncthreads();
#pragma unroll
        for (int j = 0; j < 16; ++j) {
            int b = myb[j];
            if (b >= 0) {
                int pos = sbase[b] + atomicAdd(&lcur[b], 1);
                pairs[(size_t)b * CAP + pos] = myp[j];
            }
        }
    }
}

// ============ Phase B: one block per bucket (128 nodes) ===================
__global__ __launch_bounds__(256) void k_fillB(const int* __restrict__ gcur,
                                               const int* __restrict__ pairs,
                                               int* __restrict__ rowptr,
                                               float* __restrict__ dinv,
                                               int* __restrict__ srows) {
    __shared__ int mpl[CAP];
    __shared__ int red[256];
    __shared__ int psum[CHUNK];
    __shared__ int deg[CHUNK];
    __shared__ int curs[CHUNK];
    int b = blockIdx.x, t = threadIdx.x;

    // global base = sum gcur[0..b-1]
    int part = 0;
    for (int i = t; i < NBKT; i += 256)
        if (i < b) part += gcur[i];
    red[t] = part;
    if (t < CHUNK) deg[t] = 0;
    __syncthreads();
    for (int off = 128; off; off >>= 1) {
        if (t < off) red[t] += red[t + off];
        __syncthreads();
    }
    int gb = red[0];
    int cnt = gcur[b];
    if (b == 0 && t == 0) rowptr[N_NODES] = N_EDGES;

    const int* mp = pairs + (size_t)b * CAP;

    // stage + histogram in one pass
    for (int i = t; i < cnt; i += 256) {
        int v = mp[i];
        mpl[i] = v;
        atomicAdd(&deg[v >> 17], 1);
    }
    __syncthreads();

    int d = (t < CHUNK) ? deg[t] : 0;
    if (t < CHUNK) psum[t] = d;
    __syncthreads();
    for (int off = 1; off < CHUNK; off <<= 1) {
        int u = (t >= off && t < CHUNK) ? psum[t - off] : 0;
        __syncthreads();
        if (t < CHUNK) psum[t] += u;
        __syncthreads();
    }
    if (t < CHUNK) {
        int o = gb + psum[t] - d;                 // exclusive
        curs[t] = o;
        int node = (b << CHUNK_LG) + t;
        if (node < N_NODES) {
            rowptr[node] = o;
            dinv[node] = rsqrtf(1.f + (float)d);
        }
    }
    __syncthreads();
    for (int i = t; i < cnt; i += 256) {
        int v = mpl[i];
        int pos = atomicAdd(&curs[v >> 17], 1);
        srows[pos] = v & 0x1FFFF;
    }
}

// ============ layer-2 GEMM: h2 = relu(agg1+b1)@W2, f16 out ================
template<int NOUT>
__global__ __launch_bounds__(256) void k_gemm_mfma2(
    const _Float16* __restrict__ Ah, const _Float16* __restrict__ Wt,
    const float* __restrict__ b_in, _Float16* __restrict__ Hout, int nrows)
{
    constexpr int KD = K_DIM;
    constexpr int NT = NOUT / 16;
    __shared__ _Float16 Blds[NOUT][KD + 8];

    for (int i = threadIdx.x; i < NOUT * (KD / 8); i += 256) {
        int n = i >> 4, k0 = (i & 15) * 8;
        *reinterpret_cast<half8*>(&Blds[n][k0]) =
            *reinterpret_cast<const half8*>(Wt + (size_t)n * KD + k0);
    }
    __syncthreads();

    const int wave = threadIdx.x >> 6;
    const int lane = threadIdx.x & 63;
    const int r16  = lane & 15;
    const int kg   = lane >> 4;
    const int arow = blockIdx.x * 64 + wave * 16 + r16;
    const bool rowok = arow < nrows;

    f32x4 acc[NT];
#pragma unroll
    for (int ct = 0; ct < NT; ++ct) acc[ct] = (f32x4){0.f, 0.f, 0.f, 0.f};

#pragma unroll
    for (int kc = 0; kc < KD / 32; ++kc) {
        const int k0 = kc * 32 + kg * 8;
        uint4 raw = make_uint4(0, 0, 0, 0);
        if (rowok)
            raw = *reinterpret_cast<const uint4*>(Ah + (size_t)arow * KD + k0);
        union { uint4 u; _Float16 h[8]; } U; U.u = raw;
        float4 bA = *reinterpret_cast<const float4*>(b_in + k0);
        float4 bB = *reinterpret_cast<const float4*>(b_in + k0 + 4);
        half8 a;
        a[0] = (_Float16)fmaxf((float)U.h[0] + bA.x, 0.f);
        a[1] = (_Float16)fmaxf((float)U.h[1] + bA.y, 0.f);
        a[2] = (_Float16)fmaxf((float)U.h[2] + bA.z, 0.f);
        a[3] = (_Float16)fmaxf((float)U.h[3] + bA.w, 0.f);
        a[4] = (_Float16)fmaxf((float)U.h[4] + bB.x, 0.f);
        a[5] = (_Float16)fmaxf((float)U.h[5] + bB.y, 0.f);
        a[6] = (_Float16)fmaxf((float)U.h[6] + bB.z, 0.f);
        a[7] = (_Float16)fmaxf((float)U.h[7] + bB.w, 0.f);
#pragma unroll
        for (int ct = 0; ct < NT; ++ct) {
            half8 b = *reinterpret_cast<const half8*>(&Blds[ct * 16 + r16][k0]);
            acc[ct] = __builtin_amdgcn_mfma_f32_16x16x32_f16(a, b, acc[ct], 0, 0, 0);
        }
    }

    const int orow0 = blockIdx.x * 64 + wave * 16 + kg * 4;
#pragma unroll
    for (int r = 0; r < 4; ++r) {
        int orow = orow0 + r;
        if (orow < nrows) {
#pragma unroll
            for (int ct = 0; ct < NT; ++ct)
                Hout[(size_t)orow * NOUT + ct * 16 + r16] = (_Float16)acc[ct][r];
        }
    }
}

// ---------------- gather (f16 source): TWO nodes per wave ----------------
__device__ __forceinline__ void fma8(uint4 v, float wgt, float (&acc)[8]) {
    union { uint4 u; _Float16 h[8]; } U;
    U.u = v;
#pragma unroll
    for (int j = 0; j < 8; ++j)
        acc[j] = fmaf((float)U.h[j], wgt, acc[j]);
}

// OUT[i] = sum_e H[row_e]*dinv_r*dinv_i + H[i]*dinv_i^2 (+bias)
// Each 32-lane half-wave owns one destination node.
template<int F, bool OUT_HALF>
__global__ __launch_bounds__(256) void k_gather_h(
    const int* __restrict__ rowptr, const int* __restrict__ srows,
    const float* __restrict__ dinv, const _Float16* __restrict__ H,
    const float* __restrict__ bias, void* __restrict__ OUT, int n)
{
    constexpr int LPR = F / 8;     // lanes per row (16 or 8)
    constexpr int GR  = 32 / LPR;  // rows per half-wave load (2 or 4)
    int lane = threadIdx.x & 63;
    int half = lane >> 5;
    int hl   = lane & 31;
    int w = blockIdx.x * 8 + (threadIdx.x >> 6) * 2 + half;
    if (w >= n) return;
    int g = hl / LPR;              // row group within half-wave
    int c = hl % LPR;              // uint4 slot within row
    float di = dinv[w];
    int s = rowptr[w], e = rowptr[w + 1];
    const uint4* Hp = reinterpret_cast<const uint4*>(H);

    float acc[8];
#pragma unroll
    for (int j = 0; j < 8; ++j) acc[j] = 0.f;
    uint4 hv = Hp[(size_t)w * LPR + c];                 // self row
    fma8(hv, (g == 0) ? di * di : 0.f, acc);

    if (s < e) {
        int k0 = s + g;
        int kc = min(k0, e - 1);
        int r  = srows[kc];
        float wcur = (k0 < e) ? dinv[r] * di : 0.f;
        uint4 hcur = Hp[(size_t)r * LPR + c];
        for (int k = s + GR; k < e; k += GR) {
            int k1  = k + g;
            int kc1 = min(k1, e - 1);
            int r1  = srows[kc1];
            float wnxt = (k1 < e) ? dinv[r1] * di : 0.f;
            uint4 hnxt = Hp[(size_t)r1 * LPR + c];
            fma8(hcur, wcur, acc);
            wcur = wnxt; hcur = hnxt;
        }
        fma8(hcur, wcur, acc);
    }

#pragma unroll
    for (int m = 16; m >= LPR; m >>= 1) {               // combine row groups
#pragma unroll
        for (int j = 0; j < 8; ++j)
            acc[j] += __shfl_xor(acc[j], m, 64);
    }

    if (g == 0) {
        if constexpr (OUT_HALF) {
            union { uint4 u; __half2 h[4]; } P;
#pragma unroll
            for (int j = 0; j < 4; ++j)
                P.h[j] = __floats2half2_rn(acc[2 * j], acc[2 * j + 1]);
            reinterpret_cast<uint4*>(OUT)[(size_t)w * LPR + c] = P.u;
        } else {
            const float4* bp = reinterpret_cast<const float4*>(bias + c * 8);
            float4 b0 = bp[0], b1v = bp[1];
            float4 o0 = make_float4(acc[0] + b0.x, acc[1] + b0.y,
                                    acc[2] + b0.z, acc[3] + b0.w);
            float4 o1 = make_float4(acc[4] + b1v.x, acc[5] + b1v.y,
                                    acc[6] + b1v.z, acc[7] + b1v.w);
            float* op = (float*)OUT + (size_t)w * F + c * 8;
            *reinterpret_cast<float4*>(op)     = o0;
            *reinterpret_cast<float4*>(op + 4) = o1;
        }
    }
}

// ---------------- launch ----------------

extern "C" void kernel_launch(void* const* d_in, const int* in_sizes, int n_in,
                              void* d_out, int out_size, void* d_ws, size_t ws_size,
                              hipStream_t stream) {
    const float* x  = (const float*)d_in[0];
    const int*   ei = (const int*)  d_in[1];
    const float* W1 = (const float*)d_in[2];
    const float* b1 = (const float*)d_in[3];
    const float* W2 = (const float*)d_in[4];
    const float* b2 = (const float*)d_in[5];
    float* out = (float*)d_out;

    const int* row = ei;             // sources
    const int* col = ei + N_EDGES;   // targets

    // workspace layout
    char* ws = (char*)d_ws;
    int*   gcur   = (int*)ws;                                      // NBKT (782)
    int*   rowptr = gcur + 1024;                                   // N+1
    float* dinv   = (float*)(rowptr + ((N_NODES + 256) & ~255));   // N
    int*   srows  = (int*)(dinv + ((N_NODES + 255) & ~255));       // E
    _Float16* bufH  = (_Float16*)(srows + ((N_EDGES + 255) & ~255)); // N*128 (h1)
    _Float16* bufAgg = bufH + (size_t)N_NODES * 128;               // N*128 (agg1)
    _Float16* bufH2  = bufAgg + (size_t)N_NODES * 128;             // N*64 (h2)
    _Float16* Wt1 = bufH2 + (size_t)N_NODES * 64;                  // 128*128
    _Float16* Wt2 = Wt1 + 128 * 128;                               // 64*128
    int*   pairs  = (int*)(Wt2 + 64 * 128 + 256);                  // NBKT*CAP (8MB)

    // 0) W -> f16 transposed + zero bucket cursors (one launch)
    k_prepW<<<16, 256, 0, stream>>>(W1, W2, Wt1, Wt2, gcur);

    // 1) fused gemm1 ∥ edge bucketing (1:4 interleave)
    k_gemm1_bucket<<<NBLK_TOT, 256, 0, stream>>>(
        x, Wt1, bufH, row, col, gcur, pairs);

    // 2) CSR finalize: rowptr, dinv, srows (782 blocks)
    k_fillB<<<NBKT, 256, 0, stream>>>(gcur, pairs, rowptr, dinv, srows);

    // 3) agg1 = gather(h1), f16 out  (2 nodes per wave)
    k_gather_h<128, true><<<(N_NODES + 7) / 8, 256, 0, stream>>>(
        rowptr, srows, dinv, bufH, nullptr, bufAgg, N_NODES);

    // 4) h2 = relu(agg1+b1)@W2 (f16 out)
    k_gemm_mfma2<64><<<(N_NODES + 63) / 64, 256, 0, stream>>>(
        bufAgg, Wt2, b1, bufH2, N_NODES);

    // 5) out = gather(h2) + b2 (fp32 out, 2 nodes per wave)
    k_gather_h<64, false><<<(N_NODES + 7) / 8, 256, 0, stream>>>(
        rowptr, srows, dinv, bufH2, b2, out, N_NODES);
}